// Round 2
// baseline (610.489 us; speedup 1.0000x reference)
//
#include <hip/hip_runtime.h>
#include <hip/hip_bf16.h>
#include <stdint.h>

// MoE: T=4096 tokens, D_MODEL=1024, D_FF=4096, E=8, top-2.
// Sparse grouped-GEMM pipeline, bf16 MFMA compute, fp32 gating.

#define T_TOK 4096
#define DM 1024
#define DF 4096
#define NE 8
#define BM 128
#define BN 128
#define BK 64
#define BN2 64              // gemm2 N-tile
#define MAX_TILES 72        // sum ceil(count_e/128) <= 64 + 8
#define PAIR_CAP 9216       // MAX_TILES * 128

typedef __bf16 bf16x8 __attribute__((ext_vector_type(8)));
typedef float f32x4 __attribute__((ext_vector_type(4)));
typedef unsigned short ushort_t;

__device__ __forceinline__ ushort_t f2bf(float f) {
  uint32_t u = __float_as_uint(f);
  u += 0x7FFFu + ((u >> 16) & 1u);   // RNE
  return (ushort_t)(u >> 16);
}

// ---- workspace layout (bytes) ----
// pair_out overlaps w1t: w1t is dead once gemm1 finishes; gemm2/combine reuse it.
#define W1T_OFF 0ull                  // [E][DF][DM] bf16 = 64MiB
#define PO_OFF  0ull                  // [PAIR_CAP][DM] f32 = 36MiB (aliases w1t)
#define W2T_OFF 67108864ull           // [E][DM][DF] bf16 = 64MiB
#define XB_OFF  134217728ull          // [T][DM] bf16 = 8MiB
#define H_OFF   142606336ull          // [PAIR_CAP][DF] bf16 = 72MiB
#define RT_OFF  218103808ull          // routing block
// routing sub-offsets (bytes from RT_OFF)
#define RO_COUNTS   0
#define RO_OFFSETS  32
#define RO_CURSORS  64
#define RO_NTILES   96
#define RO_TILE_E   128
#define RO_TILE_S   416
#define RO_TILE_R   704
#define RO_PTOK     1024
#define RO_PW       37888
#define RO_TOPI     74752
#define RO_TOPW     107520
#define RO_PIDX     140288
#define RT_BYTES    173056ull
#define WS_NEEDED   (RT_OFF + RT_BYTES)

// ------------------------------------------------------------------
// 1. Gating: one wave per token. fp32 dot products, top-2, softmax.
// ------------------------------------------------------------------
__global__ void gate_kernel(const float* __restrict__ x, const float* __restrict__ gw,
                            int* __restrict__ counts, int* __restrict__ topi,
                            float* __restrict__ topw) {
  int wave = threadIdx.x >> 6;
  int lane = threadIdx.x & 63;
  int t = blockIdx.x * 4 + wave;
  const float* xr = x + (size_t)t * DM;
  float acc[NE];
#pragma unroll
  for (int e = 0; e < NE; ++e) acc[e] = 0.f;
  for (int d = lane; d < DM; d += 64) {
    float xv = xr[d];
    const float* g = gw + (size_t)d * NE;
#pragma unroll
    for (int e = 0; e < NE; ++e) acc[e] += xv * g[e];
  }
#pragma unroll
  for (int off = 32; off > 0; off >>= 1) {
#pragma unroll
    for (int e = 0; e < NE; ++e) acc[e] += __shfl_xor(acc[e], off, 64);
  }
  if (lane == 0) {
    int i0 = 0; float v0 = acc[0];
#pragma unroll
    for (int e = 1; e < NE; ++e) if (acc[e] > v0) { v0 = acc[e]; i0 = e; }
    int i1 = -1; float v1 = -1e30f;
#pragma unroll
    for (int e = 0; e < NE; ++e) if (e != i0 && acc[e] > v1) { v1 = acc[e]; i1 = e; }
    float e1 = expf(v1 - v0);          // <= 1
    float w0 = 1.f / (1.f + e1);
    float w1 = e1 / (1.f + e1);
    topi[t * 2] = i0; topi[t * 2 + 1] = i1;
    topw[t * 2] = w0; topw[t * 2 + 1] = w1;
    atomicAdd(&counts[i0], 1);
    atomicAdd(&counts[i1], 1);
  }
}

// ------------------------------------------------------------------
// 2. Scan: padded per-expert offsets + tile list (single thread; E=8)
// ------------------------------------------------------------------
__global__ void scan_kernel(const int* __restrict__ counts, int* __restrict__ offsets,
                            int* __restrict__ cursors, int* __restrict__ n_tiles,
                            int* __restrict__ tile_e, int* __restrict__ tile_s,
                            int* __restrict__ tile_r) {
  if (threadIdx.x == 0) {
    int off = 0, nt = 0;
    for (int e = 0; e < NE; ++e) {
      offsets[e] = off;
      cursors[e] = 0;
      int c = counts[e];
      for (int m0 = 0; m0 < c; m0 += BM) {
        tile_e[nt] = e;
        tile_s[nt] = off + m0;
        tile_r[nt] = (c - m0 < BM) ? (c - m0) : BM;
        ++nt;
      }
      off += ((c + BM - 1) / BM) * BM;   // padded region per expert
    }
    *n_tiles = nt;
  }
}

// ------------------------------------------------------------------
// 3. Scatter tokens into per-expert pair slots (+ reverse map pidx)
// ------------------------------------------------------------------
__global__ void scatter_kernel(const int* __restrict__ topi, const float* __restrict__ topw,
                               const int* __restrict__ offsets, int* __restrict__ cursors,
                               int* __restrict__ ptok, float* __restrict__ pw,
                               int* __restrict__ pidx) {
  int t = blockIdx.x * 256 + threadIdx.x;
  if (t >= T_TOK) return;
#pragma unroll
  for (int k = 0; k < 2; ++k) {
    int e = topi[t * 2 + k];
    int pos = atomicAdd(&cursors[e], 1);
    int p = offsets[e] + pos;
    ptok[p] = t;
    pw[p] = topw[t * 2 + k];
    pidx[t * 2 + k] = p;
  }
}

// ------------------------------------------------------------------
// 4a. x fp32 -> bf16 (vectorized)
// ------------------------------------------------------------------
__global__ void convert_x(const float* __restrict__ x, ushort_t* __restrict__ xb) {
  size_t i = ((size_t)blockIdx.x * 256 + threadIdx.x) * 8;
  float4 a = *(const float4*)&x[i];
  float4 b = *(const float4*)&x[i + 4];
  ushort4 lo = { f2bf(a.x), f2bf(a.y), f2bf(a.z), f2bf(a.w) };
  ushort4 hi = { f2bf(b.x), f2bf(b.y), f2bf(b.z), f2bf(b.w) };
  *(ushort4*)&xb[i] = lo;
  *(ushort4*)&xb[i + 4] = hi;
}

// ------------------------------------------------------------------
// 4b. weights: fp32 [E][R][C] -> bf16 transposed [E][C][R]
// ------------------------------------------------------------------
__global__ void transpose_convert(const float* __restrict__ src, ushort_t* __restrict__ dst,
                                  int R, int C) {
  __shared__ ushort_t tile[64][72];   // padded stride breaks bank conflicts
  int e = blockIdx.z;
  src += (size_t)e * R * C;
  dst += (size_t)e * R * C;
  int c0 = blockIdx.x * 64, r0 = blockIdx.y * 64;
  int tr = threadIdx.x >> 4;          // 0..15
  int tc = (threadIdx.x & 15) << 2;   // 0,4,..,60
#pragma unroll
  for (int i = 0; i < 4; ++i) {
    int r = i * 16 + tr;
    float4 v = *(const float4*)&src[(size_t)(r0 + r) * C + c0 + tc];
    tile[tc + 0][r] = f2bf(v.x);
    tile[tc + 1][r] = f2bf(v.y);
    tile[tc + 2][r] = f2bf(v.z);
    tile[tc + 3][r] = f2bf(v.w);
  }
  __syncthreads();
#pragma unroll
  for (int i = 0; i < 4; ++i) {
    int flat = i * 256 + threadIdx.x;
    int cr = flat >> 4;               // 0..63 (C-local row of dst)
    int rg = (flat & 15) << 2;        // 0..60
    ushort4 o = { tile[cr][rg], tile[cr][rg + 1], tile[cr][rg + 2], tile[cr][rg + 3] };
    *(ushort4*)&dst[(size_t)(c0 + cr) * R + r0 + rg] = o;
  }
}

// ------------------------------------------------------------------
// 5. GEMM1: h[p][:] = relu(x[tok(p)] @ W1_e), grouped by expert tile
// ------------------------------------------------------------------
__global__ __launch_bounds__(256) void gemm1_kernel(
    const ushort_t* __restrict__ xb, const ushort_t* __restrict__ w1t,
    ushort_t* __restrict__ h,
    const int* __restrict__ n_tiles, const int* __restrict__ tile_e,
    const int* __restrict__ tile_s, const int* __restrict__ tile_r,
    const int* __restrict__ ptok) {
  int tile = blockIdx.x;
  if (tile >= *n_tiles) return;
  int e = tile_e[tile], p0 = tile_s[tile], rows = tile_r[tile];
  int n0 = blockIdx.y * BN;

  __shared__ ushort_t As[BM * BK];   // [m][k]
  __shared__ ushort_t Bs[BN * BK];   // [n][k]
  int tid = threadIdx.x, wave = tid >> 6, lane = tid & 63;

  const ushort_t* a_src[4];
  const ushort_t* b_src[4];
#pragma unroll
  for (int j = 0; j < 4; ++j) {
    int r = (wave * 4 + j) * 8 + (lane >> 3);
    int c8 = (lane & 7) * 8;
    int tok = (r < rows) ? ptok[p0 + r] : 0;
    a_src[j] = xb + (size_t)tok * DM + c8;
    b_src[j] = w1t + ((size_t)e * DF + n0 + r) * DM + c8;
  }
  f32x4 acc[4][4] = {};
  int m_off = (wave >> 1) * 64, nf_off = (wave & 1) * 64;
  int frow = lane & 15, fks = (lane >> 4) * 8;

  for (int k0 = 0; k0 < DM; k0 += BK) {
#pragma unroll
    for (int j = 0; j < 4; ++j) {
      __builtin_amdgcn_global_load_lds(
          (const __attribute__((address_space(1))) void*)(a_src[j] + k0),
          (__attribute__((address_space(3))) void*)(As + (wave * 4 + j) * 512), 16, 0, 0);
      __builtin_amdgcn_global_load_lds(
          (const __attribute__((address_space(1))) void*)(b_src[j] + k0),
          (__attribute__((address_space(3))) void*)(Bs + (wave * 4 + j) * 512), 16, 0, 0);
    }
    asm volatile("s_waitcnt vmcnt(0)" ::: "memory");
    __syncthreads();
#pragma unroll
    for (int kk = 0; kk < BK; kk += 32) {
      bf16x8 af[4], bf[4];
#pragma unroll
      for (int mi = 0; mi < 4; ++mi)
        af[mi] = *(const bf16x8*)&As[(m_off + mi * 16 + frow) * BK + kk + fks];
#pragma unroll
      for (int ni = 0; ni < 4; ++ni)
        bf[ni] = *(const bf16x8*)&Bs[(nf_off + ni * 16 + frow) * BK + kk + fks];
#pragma unroll
      for (int mi = 0; mi < 4; ++mi)
#pragma unroll
        for (int ni = 0; ni < 4; ++ni)
          acc[mi][ni] = __builtin_amdgcn_mfma_f32_16x16x32_bf16(af[mi], bf[ni], acc[mi][ni], 0, 0, 0);
    }
    __syncthreads();
  }
  // epilogue: relu -> bf16 h; zero pad rows so GEMM2 reads clean data
  int col = lane & 15;
#pragma unroll
  for (int mi = 0; mi < 4; ++mi) {
#pragma unroll
    for (int r = 0; r < 4; ++r) {
      int m = m_off + mi * 16 + (lane >> 4) * 4 + r;
      bool valid = m < rows;
      size_t rowoff = (size_t)(p0 + m) * DF + n0 + nf_off;
#pragma unroll
      for (int ni = 0; ni < 4; ++ni) {
        float v = acc[mi][ni][r];
        v = valid ? (v > 0.f ? v : 0.f) : 0.f;
        h[rowoff + ni * 16 + col] = f2bf(v);
      }
    }
  }
}

// ------------------------------------------------------------------
// 6. GEMM2: po[p][:] = pw[p] * (h[p] @ W2_e)
//    128x64 tile, double-buffered prefetch, no atomics.
// ------------------------------------------------------------------
__global__ __launch_bounds__(256) void gemm2_kernel(
    const ushort_t* __restrict__ h, const ushort_t* __restrict__ w2t,
    float* __restrict__ po,
    const int* __restrict__ n_tiles, const int* __restrict__ tile_e,
    const int* __restrict__ tile_s, const int* __restrict__ tile_r,
    const float* __restrict__ pw) {
  int tile = blockIdx.x;
  if (tile >= *n_tiles) return;
  int e = tile_e[tile], p0 = tile_s[tile], rows = tile_r[tile];
  int n0 = blockIdx.y * BN2;

  __shared__ ushort_t As[2][BM * BK];    // 2 x 16 KiB
  __shared__ ushort_t Bs[2][BN2 * BK];   // 2 x 8 KiB
  int tid = threadIdx.x, wave = tid >> 6, lane = tid & 63;

  const ushort_t* a_src[4];
  const ushort_t* b_src[2];
  int c8 = (lane & 7) * 8;
#pragma unroll
  for (int j = 0; j < 4; ++j) {
    int r = (wave * 4 + j) * 8 + (lane >> 3);
    a_src[j] = h + (size_t)(p0 + r) * DF + c8;            // pads are zeroed by gemm1
  }
#pragma unroll
  for (int j = 0; j < 2; ++j) {
    int r = (wave * 2 + j) * 8 + (lane >> 3);
    b_src[j] = w2t + ((size_t)e * DM + n0 + r) * DF + c8;
  }

  auto stage = [&](int bi, int k0) {
#pragma unroll
    for (int j = 0; j < 4; ++j)
      __builtin_amdgcn_global_load_lds(
          (const __attribute__((address_space(1))) void*)(a_src[j] + k0),
          (__attribute__((address_space(3))) void*)(&As[bi][(wave * 4 + j) * 512]), 16, 0, 0);
#pragma unroll
    for (int j = 0; j < 2; ++j)
      __builtin_amdgcn_global_load_lds(
          (const __attribute__((address_space(1))) void*)(b_src[j] + k0),
          (__attribute__((address_space(3))) void*)(&Bs[bi][(wave * 2 + j) * 512]), 16, 0, 0);
  };

  f32x4 acc[4][2] = {};
  int m_off = (wave >> 1) * 64, nf_off = (wave & 1) * 32;
  int frow = lane & 15, fks = (lane >> 4) * 8;

  stage(0, 0);
  asm volatile("s_waitcnt vmcnt(0)" ::: "memory");
  __syncthreads();
  int buf = 0;
#define NT2 (DF / BK)
  for (int t = 0; t < NT2; ++t) {
    if (t + 1 < NT2) stage(buf ^ 1, (t + 1) * BK);   // prefetch overlaps MFMA below
#pragma unroll
    for (int kk = 0; kk < BK; kk += 32) {
      bf16x8 af[4], bfr[2];
#pragma unroll
      for (int mi = 0; mi < 4; ++mi)
        af[mi] = *(const bf16x8*)&As[buf][(m_off + mi * 16 + frow) * BK + kk + fks];
#pragma unroll
      for (int ni = 0; ni < 2; ++ni)
        bfr[ni] = *(const bf16x8*)&Bs[buf][(nf_off + ni * 16 + frow) * BK + kk + fks];
#pragma unroll
      for (int mi = 0; mi < 4; ++mi)
#pragma unroll
        for (int ni = 0; ni < 2; ++ni)
          acc[mi][ni] = __builtin_amdgcn_mfma_f32_16x16x32_bf16(af[mi], bfr[ni], acc[mi][ni], 0, 0, 0);
    }
    __syncthreads();   // implicit vmcnt(0)+lgkmcnt(0) drain: prefetch landed, reads done
    buf ^= 1;
  }
  // epilogue: weighted per-pair rows (combine kernel gathers; deterministic)
  int col = lane & 15;
#pragma unroll
  for (int mi = 0; mi < 4; ++mi) {
#pragma unroll
    for (int r = 0; r < 4; ++r) {
      int m = m_off + mi * 16 + (lane >> 4) * 4 + r;
      if (m < rows) {
        int p = p0 + m;
        float w = pw[p];
        size_t o = (size_t)p * DM + n0 + nf_off;
#pragma unroll
        for (int ni = 0; ni < 2; ++ni)
          po[o + ni * 16 + col] = w * acc[mi][ni][r];
      }
    }
  }
}

// ------------------------------------------------------------------
// 7. Combine: out[t] = po[pidx[t,0]] + po[pidx[t,1]]
// ------------------------------------------------------------------
__global__ void combine_kernel(const float* __restrict__ po, const int* __restrict__ pidx,
                               float* __restrict__ out) {
  int idx = blockIdx.x * 256 + threadIdx.x;   // T_TOK * DM/4 items
  int t = idx >> 8;                           // DM/4 = 256
  int d4 = (idx & 255) << 2;
  int pa = pidx[t * 2], pb = pidx[t * 2 + 1];
  float4 a = *(const float4*)&po[(size_t)pa * DM + d4];
  float4 b = *(const float4*)&po[(size_t)pb * DM + d4];
  float4 o = { a.x + b.x, a.y + b.y, a.z + b.z, a.w + b.w };
  *(float4*)&out[(size_t)t * DM + d4] = o;
}

// ------------------------------------------------------------------
extern "C" void kernel_launch(void* const* d_in, const int* in_sizes, int n_in,
                              void* d_out, int out_size, void* d_ws, size_t ws_size,
                              hipStream_t stream) {
  const float* x  = (const float*)d_in[0];   // [2,2048,1024]
  const float* gw = (const float*)d_in[1];   // [1024,8]
  const float* w1 = (const float*)d_in[2];   // [8,1024,4096]
  const float* w2 = (const float*)d_in[3];   // [8,4096,1024]
  float* out = (float*)d_out;                // [4096,1024]
  char* ws = (char*)d_ws;
  if (ws_size < WS_NEEDED) return;           // visible failure if ws too small

  ushort_t* w1t = (ushort_t*)(ws + W1T_OFF);
  float*    po  = (float*)(ws + PO_OFF);     // aliases w1t (dead after gemm1)
  ushort_t* w2t = (ushort_t*)(ws + W2T_OFF);
  ushort_t* xb  = (ushort_t*)(ws + XB_OFF);
  ushort_t* h   = (ushort_t*)(ws + H_OFF);
  char* rt = ws + RT_OFF;
  int*   counts  = (int*)(rt + RO_COUNTS);
  int*   offsets = (int*)(rt + RO_OFFSETS);
  int*   cursors = (int*)(rt + RO_CURSORS);
  int*   n_tiles = (int*)(rt + RO_NTILES);
  int*   tile_e  = (int*)(rt + RO_TILE_E);
  int*   tile_s  = (int*)(rt + RO_TILE_S);
  int*   tile_r  = (int*)(rt + RO_TILE_R);
  int*   ptok    = (int*)(rt + RO_PTOK);
  float* pw      = (float*)(rt + RO_PW);
  int*   topi    = (int*)(rt + RO_TOPI);
  float* topw    = (float*)(rt + RO_TOPW);
  int*   pidx    = (int*)(rt + RO_PIDX);

  hipMemsetAsync(rt, 0, 128, stream);   // counts/offsets/cursors/n_tiles

  hipLaunchKernelGGL(gate_kernel, dim3(T_TOK / 4), dim3(256), 0, stream, x, gw, counts, topi, topw);
  hipLaunchKernelGGL(scan_kernel, dim3(1), dim3(64), 0, stream,
                     counts, offsets, cursors, n_tiles, tile_e, tile_s, tile_r);
  hipLaunchKernelGGL(scatter_kernel, dim3(T_TOK / 256), dim3(256), 0, stream,
                     topi, topw, offsets, cursors, ptok, pw, pidx);
  hipLaunchKernelGGL(convert_x, dim3((T_TOK * DM) / (256 * 8)), dim3(256), 0, stream, x, xb);
  hipLaunchKernelGGL(transpose_convert, dim3(DF / 64, DM / 64, NE), dim3(256), 0, stream,
                     w1, w1t, DM, DF);
  hipLaunchKernelGGL(transpose_convert, dim3(DM / 64, DF / 64, NE), dim3(256), 0, stream,
                     w2, w2t, DF, DM);
  hipLaunchKernelGGL(gemm1_kernel, dim3(MAX_TILES, DF / BN), dim3(256), 0, stream,
                     xb, w1t, h, n_tiles, tile_e, tile_s, tile_r, ptok);
  hipLaunchKernelGGL(gemm2_kernel, dim3(MAX_TILES, DM / BN2), dim3(256), 0, stream,
                     h, w2t, po, n_tiles, tile_e, tile_s, tile_r, pw);
  hipLaunchKernelGGL(combine_kernel, dim3((T_TOK * DM / 4) / 256), dim3(256), 0, stream,
                     po, pidx, out);
}

// Round 3
// 481.992 us; speedup vs baseline: 1.2666x; 1.2666x over previous
//
#include <hip/hip_runtime.h>
#include <hip/hip_bf16.h>
#include <stdint.h>

// MoE: T=4096 tokens, D_MODEL=1024, D_FF=4096, E=8, top-2.
// Sparse grouped-GEMM, bf16 MFMA, 256x256 tiles, counted-vmcnt pipeline.

#define T_TOK 4096
#define DM 1024
#define DF 4096
#define NE 8
#define BM 256              // M tile (pair rows)
#define BK 64               // K step
#define MAX_TILES 40        // sum ceil(c_e/256) <= 32 + 8
#define PAIR_CAP 10240      // MAX_TILES * 256

typedef __bf16 bf16x8 __attribute__((ext_vector_type(8)));
typedef float f32x4 __attribute__((ext_vector_type(4)));
typedef unsigned short ushort_t;

__device__ __forceinline__ ushort_t f2bf(float f) {
  uint32_t u = __float_as_uint(f);
  u += 0x7FFFu + ((u >> 16) & 1u);   // RNE
  return (ushort_t)(u >> 16);
}

// ---- workspace layout (bytes) ----
// Region A (64MiB): w1t until gemm1 done, then w2t (transpose_w2 runs between).
#define WT_OFF  0ull                 // [E][*][*] bf16 = 64MiB (w1t, then w2t)
#define XB_OFF  67108864ull          // [T][DM] bf16 = 8MiB
#define H_OFF   75497472ull          // [PAIR_CAP][DF] bf16 = 80MiB
#define PO_OFF  159383552ull         // [PAIR_CAP][DM] f32 = 40MiB
#define RT_OFF  201326592ull         // routing block
// routing sub-offsets (bytes from RT_OFF)
#define RO_COUNTS   0
#define RO_OFFSETS  32
#define RO_CURSORS  64
#define RO_NTILES   96
#define RO_TILE_E   128
#define RO_TILE_S   320
#define RO_TILE_R   512
#define RO_PTOK     1024             // PAIR_CAP*4 = 40960
#define RO_PW       41984            // 40960
#define RO_TOPI     82944            // 32768
#define RO_TOPW     115712           // 32768
#define RO_PIDX     148480           // 32768
#define RT_BYTES    181248ull
#define WS_NEEDED   (RT_OFF + RT_BYTES)

// ------------------------------------------------------------------
// 1. Gating
// ------------------------------------------------------------------
__global__ void gate_kernel(const float* __restrict__ x, const float* __restrict__ gw,
                            int* __restrict__ counts, int* __restrict__ topi,
                            float* __restrict__ topw) {
  int wave = threadIdx.x >> 6;
  int lane = threadIdx.x & 63;
  int t = blockIdx.x * 4 + wave;
  const float* xr = x + (size_t)t * DM;
  float acc[NE];
#pragma unroll
  for (int e = 0; e < NE; ++e) acc[e] = 0.f;
  for (int d = lane; d < DM; d += 64) {
    float xv = xr[d];
    const float* g = gw + (size_t)d * NE;
#pragma unroll
    for (int e = 0; e < NE; ++e) acc[e] += xv * g[e];
  }
#pragma unroll
  for (int off = 32; off > 0; off >>= 1) {
#pragma unroll
    for (int e = 0; e < NE; ++e) acc[e] += __shfl_xor(acc[e], off, 64);
  }
  if (lane == 0) {
    int i0 = 0; float v0 = acc[0];
#pragma unroll
    for (int e = 1; e < NE; ++e) if (acc[e] > v0) { v0 = acc[e]; i0 = e; }
    int i1 = -1; float v1 = -1e30f;
#pragma unroll
    for (int e = 0; e < NE; ++e) if (e != i0 && acc[e] > v1) { v1 = acc[e]; i1 = e; }
    float e1 = expf(v1 - v0);
    float w0 = 1.f / (1.f + e1);
    float w1 = e1 / (1.f + e1);
    topi[t * 2] = i0; topi[t * 2 + 1] = i1;
    topw[t * 2] = w0; topw[t * 2 + 1] = w1;
    atomicAdd(&counts[i0], 1);
    atomicAdd(&counts[i1], 1);
  }
}

// ------------------------------------------------------------------
// 2. Scan: padded (to 256) per-expert offsets + tile list
// ------------------------------------------------------------------
__global__ void scan_kernel(const int* __restrict__ counts, int* __restrict__ offsets,
                            int* __restrict__ cursors, int* __restrict__ n_tiles,
                            int* __restrict__ tile_e, int* __restrict__ tile_s,
                            int* __restrict__ tile_r) {
  if (threadIdx.x == 0) {
    int off = 0, nt = 0;
    for (int e = 0; e < NE; ++e) {
      offsets[e] = off;
      cursors[e] = 0;
      int c = counts[e];
      for (int m0 = 0; m0 < c; m0 += BM) {
        tile_e[nt] = e;
        tile_s[nt] = off + m0;
        tile_r[nt] = (c - m0 < BM) ? (c - m0) : BM;
        ++nt;
      }
      off += ((c + BM - 1) / BM) * BM;
    }
    *n_tiles = nt;
  }
}

// ------------------------------------------------------------------
// 3. Scatter tokens into pair slots (+ reverse map pidx)
// ------------------------------------------------------------------
__global__ void scatter_kernel(const int* __restrict__ topi, const float* __restrict__ topw,
                               const int* __restrict__ offsets, int* __restrict__ cursors,
                               int* __restrict__ ptok, float* __restrict__ pw,
                               int* __restrict__ pidx) {
  int t = blockIdx.x * 256 + threadIdx.x;
  if (t >= T_TOK) return;
#pragma unroll
  for (int k = 0; k < 2; ++k) {
    int e = topi[t * 2 + k];
    int pos = atomicAdd(&cursors[e], 1);
    int p = offsets[e] + pos;
    ptok[p] = t;
    pw[p] = topw[t * 2 + k];
    pidx[t * 2 + k] = p;
  }
}

// ------------------------------------------------------------------
// 4a. x fp32 -> bf16
// ------------------------------------------------------------------
__global__ void convert_x(const float* __restrict__ x, ushort_t* __restrict__ xb) {
  size_t i = ((size_t)blockIdx.x * 256 + threadIdx.x) * 8;
  float4 a = *(const float4*)&x[i];
  float4 b = *(const float4*)&x[i + 4];
  ushort4 lo = { f2bf(a.x), f2bf(a.y), f2bf(a.z), f2bf(a.w) };
  ushort4 hi = { f2bf(b.x), f2bf(b.y), f2bf(b.z), f2bf(b.w) };
  *(ushort4*)&xb[i] = lo;
  *(ushort4*)&xb[i + 4] = hi;
}

// ------------------------------------------------------------------
// 4b. weights: fp32 [E][R][C] -> bf16 transposed [E][C][R]
// ------------------------------------------------------------------
__global__ void transpose_convert(const float* __restrict__ src, ushort_t* __restrict__ dst,
                                  int R, int C) {
  __shared__ ushort_t tile[64][72];
  int e = blockIdx.z;
  src += (size_t)e * R * C;
  dst += (size_t)e * R * C;
  int c0 = blockIdx.x * 64, r0 = blockIdx.y * 64;
  int tr = threadIdx.x >> 4;
  int tc = (threadIdx.x & 15) << 2;
#pragma unroll
  for (int i = 0; i < 4; ++i) {
    int r = i * 16 + tr;
    float4 v = *(const float4*)&src[(size_t)(r0 + r) * C + c0 + tc];
    tile[tc + 0][r] = f2bf(v.x);
    tile[tc + 1][r] = f2bf(v.y);
    tile[tc + 2][r] = f2bf(v.z);
    tile[tc + 3][r] = f2bf(v.w);
  }
  __syncthreads();
#pragma unroll
  for (int i = 0; i < 4; ++i) {
    int flat = i * 256 + threadIdx.x;
    int cr = flat >> 4;
    int rg = (flat & 15) << 2;
    ushort4 o = { tile[cr][rg], tile[cr][rg + 1], tile[cr][rg + 2], tile[cr][rg + 3] };
    *(ushort4*)&dst[(size_t)(c0 + cr) * R + r0 + rg] = o;
  }
}

// ==================================================================
// 256x256 grouped GEMM core, 8 waves (2M x 4N), BK=64, dbuf LDS.
// LDS tile [256][64] bf16 with chunk^=row&7 XOR swizzle:
//  - global_load_lds dest LINEAR (wave-uniform base + lane*16)
//  - SOURCE pre-swizzled: lane fetches k-chunk (lane&7)^((lane>>3)&7)
//  - ds_read applies chunk ^= (row&7)  (row&7 == lane&7 for frag reads)
// Pipeline: 2 K-tiles in flight; vmcnt(8) counted wait (never 0 mid-loop);
// raw s_barrier (NOT __syncthreads -> would drain vmcnt(0)).
// ==================================================================

extern __shared__ ushort_t smem[];   // [2][16384] A + [2][16384] B = 128 KiB

// ------------------------------------------------------------------
// 5. GEMM1: h[p][:] = relu(x[tok(p)] @ W1_e)   (A gathered via ptok)
// ------------------------------------------------------------------
__global__ __launch_bounds__(512, 2) void gemm1_kernel(
    const ushort_t* __restrict__ xb, const ushort_t* __restrict__ w1t,
    ushort_t* __restrict__ h,
    const int* __restrict__ n_tiles, const int* __restrict__ tile_e,
    const int* __restrict__ tile_s, const int* __restrict__ tile_r,
    const int* __restrict__ ptok) {
  int tile = blockIdx.x;
  if (tile >= *n_tiles) return;
  int e = tile_e[tile], p0 = tile_s[tile], rows = tile_r[tile];
  int n0 = blockIdx.y * BM;            // BN = 256

  ushort_t* Al = smem;                 // [2][16384]
  ushort_t* Bl = smem + 32768;         // [2][16384]
  int tid = threadIdx.x, wid = tid >> 6, lane = tid & 63;
  int wr = wid >> 2, wc = wid & 3;

  // staging sources: wave wid stages A/B 1KB-blocks b = wid*4+j (rows 8b..8b+7)
  int lr = lane >> 3;                      // 0..7 row within block
  int swc = (lane & 7) ^ (lr & 7);         // pre-swizzled k-chunk
  const ushort_t* a_src[4];
  const ushort_t* b_src[4];
#pragma unroll
  for (int j = 0; j < 4; ++j) {
    int r = 32 * wid + 8 * j + lr;         // 0..255
    int tok = (r < rows) ? ptok[p0 + r] : 0;
    a_src[j] = xb + (size_t)tok * DM + swc * 8;
    b_src[j] = w1t + ((size_t)e * DF + n0 + r) * DM + swc * 8;
  }

  auto stage = [&](int bi, int k0) {
#pragma unroll
    for (int j = 0; j < 4; ++j) {
      __builtin_amdgcn_global_load_lds(
          (const __attribute__((address_space(1))) void*)(a_src[j] + k0),
          (__attribute__((address_space(3))) void*)(Al + bi * 16384 + (wid * 4 + j) * 512), 16, 0, 0);
      __builtin_amdgcn_global_load_lds(
          (const __attribute__((address_space(1))) void*)(b_src[j] + k0),
          (__attribute__((address_space(3))) void*)(Bl + bi * 16384 + (wid * 4 + j) * 512), 16, 0, 0);
    }
  };

  // frag read offsets (ushort units), swizzled
  int fr = lane & 15, ch = lane >> 4, sw = lane & 7;
  int aoff[2], boff[2];
  aoff[0] = (wr * 128 + fr) * 64 + ((ch ^ sw) * 8);
  aoff[1] = (wr * 128 + fr) * 64 + (((ch + 4) ^ sw) * 8);
  boff[0] = (wc * 64 + fr) * 64 + ((ch ^ sw) * 8);
  boff[1] = (wc * 64 + fr) * 64 + (((ch + 4) ^ sw) * 8);

  f32x4 acc[8][4] = {};

  stage(0, 0);
  stage(1, BK);
#define NT1 (DM / BK)
  for (int t = 0; t < NT1; ++t) {
    int bufo = (t & 1) * 16384;
    if (t + 1 < NT1) asm volatile("s_waitcnt vmcnt(8)" ::: "memory");
    else             asm volatile("s_waitcnt vmcnt(0)" ::: "memory");
    asm volatile("s_barrier" ::: "memory");     // tile t fully landed for all waves
#pragma unroll
    for (int kx = 0; kx < 2; ++kx) {
      bf16x8 bfr[4];
#pragma unroll
      for (int ni = 0; ni < 4; ++ni)
        bfr[ni] = *(const bf16x8*)&Bl[bufo + boff[kx] + ni * 1024];
      __builtin_amdgcn_s_setprio(1);
#pragma unroll
      for (int mi = 0; mi < 8; ++mi) {
        bf16x8 af = *(const bf16x8*)&Al[bufo + aoff[kx] + mi * 1024];
#pragma unroll
        for (int ni = 0; ni < 4; ++ni)
          acc[mi][ni] = __builtin_amdgcn_mfma_f32_16x16x32_bf16(af, bfr[ni], acc[mi][ni], 0, 0, 0);
      }
      __builtin_amdgcn_s_setprio(0);
    }
    asm volatile("s_barrier" ::: "memory");     // all waves done reading this buffer
    if (t + 2 < NT1) stage(t & 1, (t + 2) * BK);
  }

  // epilogue: relu -> bf16 h; pad rows zeroed (gemm2 reads them)
  int col = lane & 15, rq = (lane >> 4) * 4;
#pragma unroll
  for (int mi = 0; mi < 8; ++mi) {
#pragma unroll
    for (int r = 0; r < 4; ++r) {
      int m = wr * 128 + mi * 16 + rq + r;
      bool valid = m < rows;
      size_t rowoff = (size_t)(p0 + m) * DF + n0 + wc * 64;
#pragma unroll
      for (int ni = 0; ni < 4; ++ni) {
        float v = acc[mi][ni][r];
        v = valid ? (v > 0.f ? v : 0.f) : 0.f;
        h[rowoff + ni * 16 + col] = f2bf(v);
      }
    }
  }
}

// ------------------------------------------------------------------
// 6. GEMM2: po[p][:] = pw[p] * (h[p] @ W2_e)
// ------------------------------------------------------------------
__global__ __launch_bounds__(512, 2) void gemm2_kernel(
    const ushort_t* __restrict__ h, const ushort_t* __restrict__ w2t,
    float* __restrict__ po,
    const int* __restrict__ n_tiles, const int* __restrict__ tile_e,
    const int* __restrict__ tile_s, const int* __restrict__ tile_r,
    const float* __restrict__ pw) {
  int tile = blockIdx.x;
  if (tile >= *n_tiles) return;
  int e = tile_e[tile], p0 = tile_s[tile], rows = tile_r[tile];
  int n0 = blockIdx.y * BM;            // BN = 256 over DM

  ushort_t* Al = smem;
  ushort_t* Bl = smem + 32768;
  int tid = threadIdx.x, wid = tid >> 6, lane = tid & 63;
  int wr = wid >> 2, wc = wid & 3;

  int lr = lane >> 3;
  int swc = (lane & 7) ^ (lr & 7);
  const ushort_t* a_src[4];
  const ushort_t* b_src[4];
#pragma unroll
  for (int j = 0; j < 4; ++j) {
    int r = 32 * wid + 8 * j + lr;
    a_src[j] = h + (size_t)(p0 + r) * DF + swc * 8;       // pads zeroed by gemm1
    b_src[j] = w2t + ((size_t)e * DM + n0 + r) * DF + swc * 8;
  }

  auto stage = [&](int bi, int k0) {
#pragma unroll
    for (int j = 0; j < 4; ++j) {
      __builtin_amdgcn_global_load_lds(
          (const __attribute__((address_space(1))) void*)(a_src[j] + k0),
          (__attribute__((address_space(3))) void*)(Al + bi * 16384 + (wid * 4 + j) * 512), 16, 0, 0);
      __builtin_amdgcn_global_load_lds(
          (const __attribute__((address_space(1))) void*)(b_src[j] + k0),
          (__attribute__((address_space(3))) void*)(Bl + bi * 16384 + (wid * 4 + j) * 512), 16, 0, 0);
    }
  };

  int fr = lane & 15, ch = lane >> 4, sw = lane & 7;
  int aoff[2], boff[2];
  aoff[0] = (wr * 128 + fr) * 64 + ((ch ^ sw) * 8);
  aoff[1] = (wr * 128 + fr) * 64 + (((ch + 4) ^ sw) * 8);
  boff[0] = (wc * 64 + fr) * 64 + ((ch ^ sw) * 8);
  boff[1] = (wc * 64 + fr) * 64 + (((ch + 4) ^ sw) * 8);

  f32x4 acc[8][4] = {};

  stage(0, 0);
  stage(1, BK);
#define NT2 (DF / BK)
  for (int t = 0; t < NT2; ++t) {
    int bufo = (t & 1) * 16384;
    if (t + 1 < NT2) asm volatile("s_waitcnt vmcnt(8)" ::: "memory");
    else             asm volatile("s_waitcnt vmcnt(0)" ::: "memory");
    asm volatile("s_barrier" ::: "memory");
#pragma unroll
    for (int kx = 0; kx < 2; ++kx) {
      bf16x8 bfr[4];
#pragma unroll
      for (int ni = 0; ni < 4; ++ni)
        bfr[ni] = *(const bf16x8*)&Bl[bufo + boff[kx] + ni * 1024];
      __builtin_amdgcn_s_setprio(1);
#pragma unroll
      for (int mi = 0; mi < 8; ++mi) {
        bf16x8 af = *(const bf16x8*)&Al[bufo + aoff[kx] + mi * 1024];
#pragma unroll
        for (int ni = 0; ni < 4; ++ni)
          acc[mi][ni] = __builtin_amdgcn_mfma_f32_16x16x32_bf16(af, bfr[ni], acc[mi][ni], 0, 0, 0);
      }
      __builtin_amdgcn_s_setprio(0);
    }
    asm volatile("s_barrier" ::: "memory");
    if (t + 2 < NT2) stage(t & 1, (t + 2) * BK);
  }

  // epilogue: weighted per-pair rows
  int col = lane & 15, rq = (lane >> 4) * 4;
#pragma unroll
  for (int mi = 0; mi < 8; ++mi) {
#pragma unroll
    for (int r = 0; r < 4; ++r) {
      int m = wr * 128 + mi * 16 + rq + r;
      if (m < rows) {
        int p = p0 + m;
        float w = pw[p];
        size_t o = (size_t)p * DM + n0 + wc * 64;
#pragma unroll
        for (int ni = 0; ni < 4; ++ni)
          po[o + ni * 16 + col] = w * acc[mi][ni][r];
      }
    }
  }
}

// ------------------------------------------------------------------
// 7. Combine: out[t] = po[pidx[t,0]] + po[pidx[t,1]]
// ------------------------------------------------------------------
__global__ void combine_kernel(const float* __restrict__ po, const int* __restrict__ pidx,
                               float* __restrict__ out) {
  int idx = blockIdx.x * 256 + threadIdx.x;
  int t = idx >> 8;
  int d4 = (idx & 255) << 2;
  int pa = pidx[t * 2], pb = pidx[t * 2 + 1];
  float4 a = *(const float4*)&po[(size_t)pa * DM + d4];
  float4 b = *(const float4*)&po[(size_t)pb * DM + d4];
  float4 o = { a.x + b.x, a.y + b.y, a.z + b.z, a.w + b.w };
  *(float4*)&out[(size_t)t * DM + d4] = o;
}

// ------------------------------------------------------------------
extern "C" void kernel_launch(void* const* d_in, const int* in_sizes, int n_in,
                              void* d_out, int out_size, void* d_ws, size_t ws_size,
                              hipStream_t stream) {
  const float* x  = (const float*)d_in[0];   // [2,2048,1024]
  const float* gw = (const float*)d_in[1];   // [1024,8]
  const float* w1 = (const float*)d_in[2];   // [8,1024,4096]
  const float* w2 = (const float*)d_in[3];   // [8,4096,1024]
  float* out = (float*)d_out;                // [4096,1024]
  char* ws = (char*)d_ws;
  if (ws_size < WS_NEEDED) return;

  ushort_t* wt  = (ushort_t*)(ws + WT_OFF);  // w1t, then w2t (region reuse)
  ushort_t* xb  = (ushort_t*)(ws + XB_OFF);
  ushort_t* h   = (ushort_t*)(ws + H_OFF);
  float*    po  = (float*)(ws + PO_OFF);
  char* rt = ws + RT_OFF;
  int*   counts  = (int*)(rt + RO_COUNTS);
  int*   offsets = (int*)(rt + RO_OFFSETS);
  int*   cursors = (int*)(rt + RO_CURSORS);
  int*   n_tiles = (int*)(rt + RO_NTILES);
  int*   tile_e  = (int*)(rt + RO_TILE_E);
  int*   tile_s  = (int*)(rt + RO_TILE_S);
  int*   tile_r  = (int*)(rt + RO_TILE_R);
  int*   ptok    = (int*)(rt + RO_PTOK);
  float* pw      = (float*)(rt + RO_PW);
  int*   topi    = (int*)(rt + RO_TOPI);
  float* topw    = (float*)(rt + RO_TOPW);
  int*   pidx    = (int*)(rt + RO_PIDX);

  // allow 128 KiB dynamic LDS (idempotent; not a stream op, capture-safe)
  hipFuncSetAttribute((const void*)gemm1_kernel, hipFuncAttributeMaxDynamicSharedMemorySize, 131072);
  hipFuncSetAttribute((const void*)gemm2_kernel, hipFuncAttributeMaxDynamicSharedMemorySize, 131072);

  hipMemsetAsync(rt, 0, 128, stream);

  hipLaunchKernelGGL(gate_kernel, dim3(T_TOK / 4), dim3(256), 0, stream, x, gw, counts, topi, topw);
  hipLaunchKernelGGL(scan_kernel, dim3(1), dim3(64), 0, stream,
                     counts, offsets, cursors, n_tiles, tile_e, tile_s, tile_r);
  hipLaunchKernelGGL(scatter_kernel, dim3(T_TOK / 256), dim3(256), 0, stream,
                     topi, topw, offsets, cursors, ptok, pw, pidx);
  hipLaunchKernelGGL(convert_x, dim3((T_TOK * DM) / (256 * 8)), dim3(256), 0, stream, x, xb);
  hipLaunchKernelGGL(transpose_convert, dim3(DF / 64, DM / 64, NE), dim3(256), 0, stream,
                     w1, wt, DM, DF);                       // w1t into region A
  hipLaunchKernelGGL(gemm1_kernel, dim3(MAX_TILES, DF / BM), dim3(512), 131072, stream,
                     xb, wt, h, n_tiles, tile_e, tile_s, tile_r, ptok);
  hipLaunchKernelGGL(transpose_convert, dim3(DM / 64, DF / 64, NE), dim3(256), 0, stream,
                     w2, wt, DF, DM);                       // w2t reuses region A
  hipLaunchKernelGGL(gemm2_kernel, dim3(MAX_TILES, DM / BM), dim3(512), 131072, stream,
                     h, wt, po, n_tiles, tile_e, tile_s, tile_r, pw);
  hipLaunchKernelGGL(combine_kernel, dim3((T_TOK * DM / 4) / 256), dim3(256), 0, stream,
                     po, pidx, out);
}

// Round 5
// 448.288 us; speedup vs baseline: 1.3618x; 1.0752x over previous
//
#include <hip/hip_runtime.h>
#include <hip/hip_bf16.h>
#include <stdint.h>

// MoE: T=4096 tokens, D_MODEL=1024, D_FF=4096, E=8, top-2.
// Sparse grouped-GEMM, bf16 MFMA, 256x256 tiles, 8-phase counted-vmcnt pipeline.

#define T_TOK 4096
#define DM 1024
#define DF 4096
#define NE 8
#define BM 256              // M tile (pair rows), BN = 256
#define BK 64               // K step
#define MAX_TILES 40        // sum ceil(c_e/256) <= 32 + 8
#define PAIR_CAP 10240      // MAX_TILES * 256

typedef __bf16 bf16x8 __attribute__((ext_vector_type(8)));
typedef float f32x4 __attribute__((ext_vector_type(4)));
typedef unsigned short ushort_t;

__device__ __forceinline__ ushort_t f2bf(float f) {
  uint32_t u = __float_as_uint(f);
  u += 0x7FFFu + ((u >> 16) & 1u);   // RNE
  return (ushort_t)(u >> 16);
}

// ---- workspace layout (bytes) ----
#define WT_OFF  0ull                 // [E][*][*] bf16 = 64MiB (w1t, then w2t)
#define XB_OFF  67108864ull          // [T][DM] bf16 = 8MiB
#define H_OFF   75497472ull          // [PAIR_CAP][DF] bf16 = 80MiB
#define PO_OFF  159383552ull         // [PAIR_CAP][DM] f32 = 40MiB
#define RT_OFF  201326592ull         // routing block
#define RO_COUNTS   0
#define RO_OFFSETS  32
#define RO_CURSORS  64
#define RO_NTILES   96
#define RO_TILE_E   128
#define RO_TILE_S   320
#define RO_TILE_R   512
#define RO_PTOK     1024
#define RO_PW       41984
#define RO_TOPI     82944
#define RO_TOPW     115712
#define RO_PIDX     148480
#define RT_BYTES    181248ull
#define WS_NEEDED   (RT_OFF + RT_BYTES)

// XCD-chunked bijective swizzle (nwg divisible by 8): chunk of q per XCD.
__device__ __forceinline__ int xcd_swz(int orig, int q) {
  return (orig & 7) * q + (orig >> 3);
}

// ------------------------------------------------------------------
// 1. Gating
// ------------------------------------------------------------------
__global__ void gate_kernel(const float* __restrict__ x, const float* __restrict__ gw,
                            int* __restrict__ counts, int* __restrict__ topi,
                            float* __restrict__ topw) {
  int wave = threadIdx.x >> 6;
  int lane = threadIdx.x & 63;
  int t = blockIdx.x * 4 + wave;
  const float* xr = x + (size_t)t * DM;
  float acc[NE];
#pragma unroll
  for (int e = 0; e < NE; ++e) acc[e] = 0.f;
  for (int d = lane; d < DM; d += 64) {
    float xv = xr[d];
    const float* g = gw + (size_t)d * NE;
#pragma unroll
    for (int e = 0; e < NE; ++e) acc[e] += xv * g[e];
  }
#pragma unroll
  for (int off = 32; off > 0; off >>= 1) {
#pragma unroll
    for (int e = 0; e < NE; ++e) acc[e] += __shfl_xor(acc[e], off, 64);
  }
  if (lane == 0) {
    int i0 = 0; float v0 = acc[0];
#pragma unroll
    for (int e = 1; e < NE; ++e) if (acc[e] > v0) { v0 = acc[e]; i0 = e; }
    int i1 = -1; float v1 = -1e30f;
#pragma unroll
    for (int e = 0; e < NE; ++e) if (e != i0 && acc[e] > v1) { v1 = acc[e]; i1 = e; }
    float e1 = expf(v1 - v0);
    float w0 = 1.f / (1.f + e1);
    float w1 = e1 / (1.f + e1);
    topi[t * 2] = i0; topi[t * 2 + 1] = i1;
    topw[t * 2] = w0; topw[t * 2 + 1] = w1;
    atomicAdd(&counts[i0], 1);
    atomicAdd(&counts[i1], 1);
  }
}

// ------------------------------------------------------------------
// 2. Scan
// ------------------------------------------------------------------
__global__ void scan_kernel(const int* __restrict__ counts, int* __restrict__ offsets,
                            int* __restrict__ cursors, int* __restrict__ n_tiles,
                            int* __restrict__ tile_e, int* __restrict__ tile_s,
                            int* __restrict__ tile_r) {
  if (threadIdx.x == 0) {
    int off = 0, nt = 0;
    for (int e = 0; e < NE; ++e) {
      offsets[e] = off;
      cursors[e] = 0;
      int c = counts[e];
      for (int m0 = 0; m0 < c; m0 += BM) {
        tile_e[nt] = e;
        tile_s[nt] = off + m0;
        tile_r[nt] = (c - m0 < BM) ? (c - m0) : BM;
        ++nt;
      }
      off += ((c + BM - 1) / BM) * BM;
    }
    *n_tiles = nt;
  }
}

// ------------------------------------------------------------------
// 3. Scatter (+ reverse map pidx)
// ------------------------------------------------------------------
__global__ void scatter_kernel(const int* __restrict__ topi, const float* __restrict__ topw,
                               const int* __restrict__ offsets, int* __restrict__ cursors,
                               int* __restrict__ ptok, float* __restrict__ pw,
                               int* __restrict__ pidx) {
  int t = blockIdx.x * 256 + threadIdx.x;
  if (t >= T_TOK) return;
#pragma unroll
  for (int k = 0; k < 2; ++k) {
    int e = topi[t * 2 + k];
    int pos = atomicAdd(&cursors[e], 1);
    int p = offsets[e] + pos;
    ptok[p] = t;
    pw[p] = topw[t * 2 + k];
    pidx[t * 2 + k] = p;
  }
}

// ------------------------------------------------------------------
// 4a. x fp32 -> bf16
// ------------------------------------------------------------------
__global__ void convert_x(const float* __restrict__ x, ushort_t* __restrict__ xb) {
  size_t i = ((size_t)blockIdx.x * 256 + threadIdx.x) * 8;
  float4 a = *(const float4*)&x[i];
  float4 b = *(const float4*)&x[i + 4];
  ushort4 lo = { f2bf(a.x), f2bf(a.y), f2bf(a.z), f2bf(a.w) };
  ushort4 hi = { f2bf(b.x), f2bf(b.y), f2bf(b.z), f2bf(b.w) };
  *(ushort4*)&xb[i] = lo;
  *(ushort4*)&xb[i + 4] = hi;
}

// ------------------------------------------------------------------
// 4b. weights: fp32 [E][R][C] -> bf16 transposed [E][C][R]
//     128r x 64c tiles -> 256B write runs along dst rows.
// ------------------------------------------------------------------
__global__ void transpose_convert(const float* __restrict__ src, ushort_t* __restrict__ dst,
                                  int R, int C) {
  __shared__ ushort_t tile[64][136];
  int e = blockIdx.z;
  src += (size_t)e * R * C;
  dst += (size_t)e * R * C;
  int c0 = blockIdx.x * 64, r0 = blockIdx.y * 128;
  int tr = threadIdx.x >> 4;          // 0..15
  int tc = (threadIdx.x & 15) << 2;   // 0..60
#pragma unroll
  for (int i = 0; i < 8; ++i) {
    int r = i * 16 + tr;
    float4 v = *(const float4*)&src[(size_t)(r0 + r) * C + c0 + tc];
    tile[tc + 0][r] = f2bf(v.x);
    tile[tc + 1][r] = f2bf(v.y);
    tile[tc + 2][r] = f2bf(v.z);
    tile[tc + 3][r] = f2bf(v.w);
  }
  __syncthreads();
  int cr = threadIdx.x >> 5;          // 0..7
  int rg = (threadIdx.x & 31) << 2;   // 0..124
#pragma unroll
  for (int j = 0; j < 8; ++j) {
    int c = j * 8 + cr;
    ushort4 o = { tile[c][rg], tile[c][rg + 1], tile[c][rg + 2], tile[c][rg + 3] };
    *(ushort4*)&dst[(size_t)(c0 + c) * R + r0 + rg] = o;
  }
}

// ==================================================================
// 8-phase 256x256xBK64 grouped-GEMM core, 8 waves (2M x 4N).
// LDS 128KiB: A[par][rowhalf][128][64] + B[par][nhalf][128][64], bf16,
// chunk ^= (row&7) XOR swizzle (linear gload_lds dest + pre-swizzled
// global source + swizzled ds_read -- rule-21 both-sides).
// Per K-tile t (parity par=t&1), 4 phases; stages for t+1 go to par^1.
// Phase structure (RACE-FIXED vs r4): reads come AFTER barrier#1, since
// vmcnt only covers the wave's OWN stage loads; cross-wave landing is
// established by barrier#1. Explicit lgkmcnt(0)+sched_barrier(0) before
// the MFMA cluster (rule #18) and before barrier#2 (closes the parity
// reuse window: tile t+1 stages overwrite parity t).
//   q: [vmcnt(N)] ; STAGE(t+1) ; bar#1 ; ds_reads(parity t) ;
//      lgkmcnt(0)+schedbar ; setprio(1) 16 MFMA setprio(0) ; bar#2
// FIFO proof (per wave, 2 loads/stage, 4 stages/tile):
//   q0 waits vmcnt(2): newest-2 = A1(t) pair -> A0,B0,B1(t) own loads done.
//   q2 waits vmcnt(4): newest-4 = A0,B0(t+1) -> A1(t) done. Last tile: vmcnt(0).
// ==================================================================

extern __shared__ ushort_t smem[];   // 65536 ushorts = 128 KiB

#define GLD(srcp, dsto)                                                        \
  __builtin_amdgcn_global_load_lds(                                            \
      (const __attribute__((address_space(1))) void*)(srcp),                   \
      (__attribute__((address_space(3))) void*)(sm + (dsto)), 16, 0, 0)

#define STAGE_A(rh_, pn_, k_) {                                                \
  GLD(a_sp[rh_][0] + (k_), (pn_) + (rh_) * 8192 + wid * 1024);                 \
  GLD(a_sp[rh_][1] + (k_), (pn_) + (rh_) * 8192 + wid * 1024 + 512); }
#define STAGE_B(nh_, pn_, k_) {                                                \
  GLD(b_sp[nh_][0] + (k_), 32768 + (pn_) + (nh_) * 8192 + wid * 1024);         \
  GLD(b_sp[nh_][1] + (k_), 32768 + (pn_) + (nh_) * 8192 + wid * 1024 + 512); }

#define LGKM0_FENCE                                                            \
  asm volatile("s_waitcnt lgkmcnt(0)" ::: "memory");                           \
  __builtin_amdgcn_sched_barrier(0)

__device__ __forceinline__ void gemm_core(
    ushort_t* sm, const ushort_t* const (&a_sp)[2][2], const ushort_t* const (&b_sp)[2][2],
    int NT, int wid, int lane, f32x4 (&acc)[2][4][4]) {
  int wr = wid >> 2, wc = wid & 3;
  int fr = lane & 15, ch = lane >> 4, sw = lane & 7;
  int k0s = (ch ^ sw) * 8;            // kx0 swizzled chunk (ushort units)
  int k1s = ((ch + 4) ^ sw) * 8;      // kx1
  int abase = (wr * 64 + fr) * 64;                      // within a row-half region
  int bbase = (wc >> 1) * 8192 + ((wc & 1) * 64 + fr) * 64;

  // prologue: stage tile 0 (par 0) in deadline order A0,B0,B1,A1
  STAGE_A(0, 0, 0);
  STAGE_B(0, 0, 0);
  STAGE_B(1, 0, 0);
  STAGE_A(1, 0, 0);

  for (int t = 0; t < NT; ++t) {
    int Apar = (t & 1) * 16384;
    int Bpar = 32768 + Apar;
    int pn = ((t & 1) ^ 1) * 16384;
    int k1 = (t + 1) * BK;
    bool more = (t + 1 < NT);
    bf16x8 af[4], bk0[4], bk1[4];

    // ---- q0 ----
    asm volatile("s_waitcnt vmcnt(2)" ::: "memory");
    if (more) STAGE_A(0, pn, k1);
    asm volatile("s_barrier" ::: "memory");   // #1: A0,B0,B1(t) landed for ALL waves
#pragma unroll
    for (int ni = 0; ni < 4; ++ni) bk0[ni] = *(const bf16x8*)&sm[Bpar + bbase + ni * 1024 + k0s];
#pragma unroll
    for (int mi = 0; mi < 4; ++mi) af[mi] = *(const bf16x8*)&sm[Apar + abase + mi * 1024 + k0s];
    LGKM0_FENCE;
    __builtin_amdgcn_s_setprio(1);
#pragma unroll
    for (int mi = 0; mi < 4; ++mi)
#pragma unroll
      for (int ni = 0; ni < 4; ++ni)
        acc[0][mi][ni] = __builtin_amdgcn_mfma_f32_16x16x32_bf16(af[mi], bk0[ni], acc[0][mi][ni], 0, 0, 0);
    __builtin_amdgcn_s_setprio(0);
    asm volatile("s_barrier" ::: "memory");   // #2

    // ---- q1 ----
    if (more) STAGE_B(0, pn, k1);
    asm volatile("s_barrier" ::: "memory");
#pragma unroll
    for (int ni = 0; ni < 4; ++ni) bk1[ni] = *(const bf16x8*)&sm[Bpar + bbase + ni * 1024 + k1s];
#pragma unroll
    for (int mi = 0; mi < 4; ++mi) af[mi] = *(const bf16x8*)&sm[Apar + abase + mi * 1024 + k1s];
    LGKM0_FENCE;
    __builtin_amdgcn_s_setprio(1);
#pragma unroll
    for (int mi = 0; mi < 4; ++mi)
#pragma unroll
      for (int ni = 0; ni < 4; ++ni)
        acc[0][mi][ni] = __builtin_amdgcn_mfma_f32_16x16x32_bf16(af[mi], bk1[ni], acc[0][mi][ni], 0, 0, 0);
    __builtin_amdgcn_s_setprio(0);
    asm volatile("s_barrier" ::: "memory");

    // ---- q2 ----
    if (more) asm volatile("s_waitcnt vmcnt(4)" ::: "memory");
    else      asm volatile("s_waitcnt vmcnt(0)" ::: "memory");
    if (more) STAGE_B(1, pn, k1);
    asm volatile("s_barrier" ::: "memory");   // #1: A1(t) landed for ALL waves
#pragma unroll
    for (int mi = 0; mi < 4; ++mi) af[mi] = *(const bf16x8*)&sm[Apar + 8192 + abase + mi * 1024 + k0s];
    LGKM0_FENCE;
    __builtin_amdgcn_s_setprio(1);
#pragma unroll
    for (int mi = 0; mi < 4; ++mi)
#pragma unroll
      for (int ni = 0; ni < 4; ++ni)
        acc[1][mi][ni] = __builtin_amdgcn_mfma_f32_16x16x32_bf16(af[mi], bk0[ni], acc[1][mi][ni], 0, 0, 0);
    __builtin_amdgcn_s_setprio(0);
    asm volatile("s_barrier" ::: "memory");

    // ---- q3 ----
    if (more) STAGE_A(1, pn, k1);
    asm volatile("s_barrier" ::: "memory");
#pragma unroll
    for (int mi = 0; mi < 4; ++mi) af[mi] = *(const bf16x8*)&sm[Apar + 8192 + abase + mi * 1024 + k1s];
    LGKM0_FENCE;
    __builtin_amdgcn_s_setprio(1);
#pragma unroll
    for (int mi = 0; mi < 4; ++mi)
#pragma unroll
      for (int ni = 0; ni < 4; ++ni)
        acc[1][mi][ni] = __builtin_amdgcn_mfma_f32_16x16x32_bf16(af[mi], bk1[ni], acc[1][mi][ni], 0, 0, 0);
    __builtin_amdgcn_s_setprio(0);
    asm volatile("s_barrier" ::: "memory");   // #2: all parity-t reads done before
                                              // any wave stages parity t at tile t+1
  }
}

// ------------------------------------------------------------------
// 5. GEMM1: h[p][:] = relu(x[tok(p)] @ W1_e)
// ------------------------------------------------------------------
__global__ __launch_bounds__(512, 2) void gemm1_kernel(
    const ushort_t* __restrict__ xb, const ushort_t* __restrict__ w1t,
    ushort_t* __restrict__ h,
    const int* __restrict__ n_tiles, const int* __restrict__ tile_e,
    const int* __restrict__ tile_s, const int* __restrict__ tile_r,
    const int* __restrict__ ptok) {
  int wgid = xcd_swz(blockIdx.x, (MAX_TILES * 16) / 8);
  int tile = wgid >> 4;
  if (tile >= *n_tiles) return;
  int e = tile_e[tile], p0 = tile_s[tile], rows = tile_r[tile];
  int n0 = (wgid & 15) * 256;

  ushort_t* sm = smem;
  int tid = threadIdx.x, wid = tid >> 6, lane = tid & 63;
  int wr = wid >> 2, wc = wid & 3;
  int lr = lane >> 3;
  int swc = (lane & 7) ^ (lr & 7);    // pre-swizzled k-chunk for staging source

  const ushort_t* a_sp[2][2];
  const ushort_t* b_sp[2][2];
#pragma unroll
  for (int rh = 0; rh < 2; ++rh)
#pragma unroll
    for (int j = 0; j < 2; ++j) {
      int r = rh * 128 + wid * 16 + j * 8 + lr;
      int tok = (r < rows) ? ptok[p0 + r] : 0;
      a_sp[rh][j] = xb + (size_t)tok * DM + swc * 8;
      b_sp[rh][j] = w1t + ((size_t)e * DF + n0 + r) * DM + swc * 8;
    }

  f32x4 acc[2][4][4] = {};
  gemm_core(sm, a_sp, b_sp, DM / BK, wid, lane, acc);

  // epilogue: relu -> bf16 h; pad rows written as zero (gemm2 reads them)
  int col = lane & 15, rq = (lane >> 4) * 4;
#pragma unroll
  for (int rh = 0; rh < 2; ++rh)
#pragma unroll
    for (int mi = 0; mi < 4; ++mi)
#pragma unroll
      for (int r = 0; r < 4; ++r) {
        int m = rh * 128 + wr * 64 + mi * 16 + rq + r;
        bool valid = m < rows;
        size_t rowoff = (size_t)(p0 + m) * DF + n0 + wc * 64;
#pragma unroll
        for (int ni = 0; ni < 4; ++ni) {
          float v = acc[rh][mi][ni][r];
          v = valid ? (v > 0.f ? v : 0.f) : 0.f;
          h[rowoff + ni * 16 + col] = f2bf(v);
        }
      }
}

// ------------------------------------------------------------------
// 6. GEMM2: po[p][:] = pw[p] * (h[p] @ W2_e)
// ------------------------------------------------------------------
__global__ __launch_bounds__(512, 2) void gemm2_kernel(
    const ushort_t* __restrict__ h, const ushort_t* __restrict__ w2t,
    float* __restrict__ po,
    const int* __restrict__ n_tiles, const int* __restrict__ tile_e,
    const int* __restrict__ tile_s, const int* __restrict__ tile_r,
    const float* __restrict__ pw) {
  int wgid = xcd_swz(blockIdx.x, (MAX_TILES * 4) / 8);
  int tile = wgid >> 2;
  if (tile >= *n_tiles) return;
  int e = tile_e[tile], p0 = tile_s[tile], rows = tile_r[tile];
  int n0 = (wgid & 3) * 256;

  ushort_t* sm = smem;
  int tid = threadIdx.x, wid = tid >> 6, lane = tid & 63;
  int wr = wid >> 2, wc = wid & 3;
  int lr = lane >> 3;
  int swc = (lane & 7) ^ (lr & 7);

  const ushort_t* a_sp[2][2];
  const ushort_t* b_sp[2][2];
#pragma unroll
  for (int rh = 0; rh < 2; ++rh)
#pragma unroll
    for (int j = 0; j < 2; ++j) {
      int r = rh * 128 + wid * 16 + j * 8 + lr;
      a_sp[rh][j] = h + (size_t)(p0 + r) * DF + swc * 8;   // pads zeroed by gemm1
      b_sp[rh][j] = w2t + ((size_t)e * DM + n0 + r) * DF + swc * 8;
    }

  f32x4 acc[2][4][4] = {};
  gemm_core(sm, a_sp, b_sp, DF / BK, wid, lane, acc);

  int col = lane & 15, rq = (lane >> 4) * 4;
#pragma unroll
  for (int rh = 0; rh < 2; ++rh)
#pragma unroll
    for (int mi = 0; mi < 4; ++mi)
#pragma unroll
      for (int r = 0; r < 4; ++r) {
        int m = rh * 128 + wr * 64 + mi * 16 + rq + r;
        if (m < rows) {
          int p = p0 + m;
          float w = pw[p];
          size_t o = (size_t)p * DM + n0 + wc * 64;
#pragma unroll
          for (int ni = 0; ni < 4; ++ni)
            po[o + ni * 16 + col] = w * acc[rh][mi][ni][r];
        }
      }
}

// ------------------------------------------------------------------
// 7. Combine: out[t] = po[pidx[t,0]] + po[pidx[t,1]]
// ------------------------------------------------------------------
__global__ void combine_kernel(const float* __restrict__ po, const int* __restrict__ pidx,
                               float* __restrict__ out) {
  int idx = blockIdx.x * 256 + threadIdx.x;
  int t = idx >> 8;
  int d4 = (idx & 255) << 2;
  int pa = pidx[t * 2], pb = pidx[t * 2 + 1];
  float4 a = *(const float4*)&po[(size_t)pa * DM + d4];
  float4 b = *(const float4*)&po[(size_t)pb * DM + d4];
  float4 o = { a.x + b.x, a.y + b.y, a.z + b.z, a.w + b.w };
  *(float4*)&out[(size_t)t * DM + d4] = o;
}

// ------------------------------------------------------------------
extern "C" void kernel_launch(void* const* d_in, const int* in_sizes, int n_in,
                              void* d_out, int out_size, void* d_ws, size_t ws_size,
                              hipStream_t stream) {
  const float* x  = (const float*)d_in[0];   // [2,2048,1024]
  const float* gw = (const float*)d_in[1];   // [1024,8]
  const float* w1 = (const float*)d_in[2];   // [8,1024,4096]
  const float* w2 = (const float*)d_in[3];   // [8,4096,1024]
  float* out = (float*)d_out;                // [4096,1024]
  char* ws = (char*)d_ws;
  if (ws_size < WS_NEEDED) return;

  ushort_t* wt  = (ushort_t*)(ws + WT_OFF);  // w1t, then w2t (region reuse)
  ushort_t* xb  = (ushort_t*)(ws + XB_OFF);
  ushort_t* h   = (ushort_t*)(ws + H_OFF);
  float*    po  = (float*)(ws + PO_OFF);
  char* rt = ws + RT_OFF;
  int*   counts  = (int*)(rt + RO_COUNTS);
  int*   offsets = (int*)(rt + RO_OFFSETS);
  int*   cursors = (int*)(rt + RO_CURSORS);
  int*   n_tiles = (int*)(rt + RO_NTILES);
  int*   tile_e  = (int*)(rt + RO_TILE_E);
  int*   tile_s  = (int*)(rt + RO_TILE_S);
  int*   tile_r  = (int*)(rt + RO_TILE_R);
  int*   ptok    = (int*)(rt + RO_PTOK);
  float* pw      = (float*)(rt + RO_PW);
  int*   topi    = (int*)(rt + RO_TOPI);
  float* topw    = (float*)(rt + RO_TOPW);
  int*   pidx    = (int*)(rt + RO_PIDX);

  hipFuncSetAttribute((const void*)gemm1_kernel, hipFuncAttributeMaxDynamicSharedMemorySize, 131072);
  hipFuncSetAttribute((const void*)gemm2_kernel, hipFuncAttributeMaxDynamicSharedMemorySize, 131072);

  hipMemsetAsync(rt, 0, 128, stream);

  hipLaunchKernelGGL(gate_kernel, dim3(T_TOK / 4), dim3(256), 0, stream, x, gw, counts, topi, topw);
  hipLaunchKernelGGL(scan_kernel, dim3(1), dim3(64), 0, stream,
                     counts, offsets, cursors, n_tiles, tile_e, tile_s, tile_r);
  hipLaunchKernelGGL(scatter_kernel, dim3(T_TOK / 256), dim3(256), 0, stream,
                     topi, topw, offsets, cursors, ptok, pw, pidx);
  hipLaunchKernelGGL(convert_x, dim3((T_TOK * DM) / (256 * 8)), dim3(256), 0, stream, x, xb);
  hipLaunchKernelGGL(transpose_convert, dim3(DF / 64, DM / 128, NE), dim3(256), 0, stream,
                     w1, wt, DM, DF);                       // w1t into region A
  hipLaunchKernelGGL(gemm1_kernel, dim3(MAX_TILES * 16), dim3(512), 131072, stream,
                     xb, wt, h, n_tiles, tile_e, tile_s, tile_r, ptok);
  hipLaunchKernelGGL(transpose_convert, dim3(DM / 64, DF / 128, NE), dim3(256), 0, stream,
                     w2, wt, DF, DM);                       // w2t reuses region A
  hipLaunchKernelGGL(gemm2_kernel, dim3(MAX_TILES * 4), dim3(512), 131072, stream,
                     h, wt, po, n_tiles, tile_e, tile_s, tile_r, pw);
  hipLaunchKernelGGL(combine_kernel, dim3((T_TOK * DM / 4) / 256), dim3(256), 0, stream,
                     po, pidx, out);
}